// Round 7
// baseline (289.704 us; speedup 1.0000x reference)
//
#include <hip/hip_runtime.h>

// Fused 2-layer GRU, round 7: ILP-2 (two batch groups per wave).
// S=256, B=8192, IN=1, H=32, L=2.
//
// 256 blocks x 256 thr (4 waves); block owns 32 batch = 2 groups of 16.
// Waves 0,1: layer 0 (gate-row half 16*wl) for BOTH groups.
// Waves 2,3: layer 1, lagged one step, for BOTH groups.
// The two groups' MFMA+epilogue chains are independent -> in-wave ILP fills
// the dependency stalls that cross-block TLP couldn't (R5/R6 plateau at
// VALUBusy ~59%). One barrier per iteration serves both groups.
// h exchanged via LDS in bf16 (B-fragment direct read, zero repack).
// x staged as bf16 (16 KB), y fp32 (32 KB), h x2 double-buffered (10 KB):
// total ~58 KB static LDS (under the 64 KB static cap).
// y(i-1) computed by waves 0/1 (one per group) from the post-barrier bf16
// h1 row -- balances wave work (w01: 6 MFMA + y, w23: 12 MFMA).

#define S_LEN 256
#define B_SZ  8192
#define H_SZ  32
#define RS    40     // h-exchange row stride in shorts (80 B)

typedef __attribute__((ext_vector_type(8))) short short8;  // 8 bf16
typedef __attribute__((ext_vector_type(4))) float f32x4;   // MFMA C/D

#define MFMA(a, b, c) __builtin_amdgcn_mfma_f32_16x16x32_bf16(a, b, c, 0, 0, 0)

#if __has_builtin(__builtin_amdgcn_exp2f)
#define EXP2F(x) __builtin_amdgcn_exp2f(x)
#else
#define EXP2F(x) exp2f(x)
#endif
#if __has_builtin(__builtin_amdgcn_rcpf)
#define RCPF(x) __builtin_amdgcn_rcpf(x)
#else
#define RCPF(x) (1.0f / (x))
#endif

__device__ __forceinline__ float sigm_pre(float p) {   // p = -log2e * v
    return RCPF(1.0f + EXP2F(p));
}
__device__ __forceinline__ float tanh_pre(float p) {   // p = 2*log2e * v
    return 1.0f - 2.0f * RCPF(1.0f + EXP2F(p));
}

__device__ __forceinline__ unsigned short bf_rne1(float f) {
    union { float f; unsigned u; } x; x.f = f;
    unsigned u = x.u + 0x7fffu + ((x.u >> 16) & 1u);
    return (unsigned short)(u >> 16);
}

#if __has_builtin(__builtin_amdgcn_cvt_pk_bf16_f32)
typedef __bf16 bf16x2 __attribute__((ext_vector_type(2)));
__device__ __forceinline__ unsigned pk2(float a, float b) {
    union { bf16x2 v; unsigned u; } c;
    c.v = __builtin_amdgcn_cvt_pk_bf16_f32(a, b);
    return c.u;
}
#else
__device__ __forceinline__ unsigned pk2(float a, float b) {
    return (unsigned)bf_rne1(a) | ((unsigned)bf_rne1(b) << 16);
}
#endif

__device__ __forceinline__ float bits_f(unsigned u) {
    union { unsigned u; float f; } x; x.u = u; return x.f;
}

__global__ __launch_bounds__(256) void gru_ilp2(
    const float* __restrict__ x,      // (S,B,1)
    const float* __restrict__ h_in,   // (2,B,H)
    const float* __restrict__ W_ih0,  // (96,1)
    const float* __restrict__ W_hh0,  // (96,32)
    const float* __restrict__ b_ih0,  // (96)
    const float* __restrict__ b_hh0,  // (96)
    const float* __restrict__ W_ih1,  // (96,32)
    const float* __restrict__ W_hh1,  // (96,32)
    const float* __restrict__ b_ih1,  // (96)
    const float* __restrict__ b_hh1,  // (96)
    const float* __restrict__ W_out,  // (1,32)
    const float* __restrict__ b_out,  // (1)
    float* __restrict__ out)          // y (S*B) then h_state (2,B,H)
{
    __shared__ __align__(16) unsigned short sxs[S_LEN * 32];   // bf16 x, 16 KB
    __shared__ __align__(16) float sy[S_LEN * 32];             // fp32 y, 32 KB
    __shared__ __align__(16) unsigned short sh0s[2][32 * RS];  // h0 bf16
    __shared__ __align__(16) unsigned short sh1s[2][32 * RS];  // h1 bf16

    const int tid  = threadIdx.x;
    const int w    = tid >> 6;        // 0,1 -> layer 0; 2,3 -> layer 1
    const int lane = tid & 63;
    const int n    = lane & 15;       // batch col within group / A-row index
    const int q    = lane >> 4;       // quad
    const int base = blockIdx.x * 32;
    const int wl   = w & 1;           // gate-row half within the layer

    // ---- stage x into LDS as bf16 (one-time, coalesced) ----
    for (int s = tid; s < S_LEN * 8; s += 256) {
        const int t = s >> 3, c = s & 7;
        const float4 v = *(const float4*)&x[t * B_SZ + base + c * 4];
        *(uint2*)&sxs[t * 32 + c * 4] =
            make_uint2(pk2(v.x, v.y), pk2(v.z, v.w));
    }

    const float SRZ = -1.4426950408889634f;  // -log2(e)   (sigmoid gates)
    const float SN  =  2.8853900817779268f;  //  2*log2(e) (tanh gate)

    // ---- per-role persistent weights (shared across both groups) ----
    short8 A_h[3], A_i[3];
    f32x4  C_h[3], C_i3;
    float  wi0r[4], wi0z[4], wi0n[4], bi0n[4];   // L0 input weights (w01)
    float  wo8[8];                                // head weights (w01 y-dot)
    float  hd[2][4];                              // own h half, fp32, per group

    if (w < 2) {
#pragma unroll
        for (int t = 0; t < 3; ++t) {
            const float sc = (t < 2) ? SRZ : SN;
            const int row = 32 * t + 16 * wl + n;
#pragma unroll
            for (int e = 0; e < 8; ++e)
                A_h[t][e] = (short)bf_rne1(W_hh0[row * H_SZ + q * 8 + e] * sc);
#pragma unroll
            for (int r = 0; r < 4; ++r) {
                const int g = 32 * t + 16 * wl + 4 * q + r;
                C_h[t][r] = (t < 2) ? SRZ * (b_ih0[g] + b_hh0[g])
                                    : SN * b_hh0[g];
            }
        }
#pragma unroll
        for (int r = 0; r < 4; ++r) {
            const int j = 16 * wl + 4 * q + r;
            wi0r[r] = SRZ * W_ih0[j];
            wi0z[r] = SRZ * W_ih0[32 + j];
            wi0n[r] = SN  * W_ih0[64 + j];
            bi0n[r] = SN  * b_ih0[64 + j];
        }
#pragma unroll
        for (int e = 0; e < 8; ++e) wo8[e] = W_out[q * 8 + e];
#pragma unroll
        for (int g = 0; g < 2; ++g)
#pragma unroll
            for (int r = 0; r < 4; ++r)
                hd[g][r] = h_in[(base + g * 16 + n) * H_SZ + 16 * wl + 4 * q + r];
    } else {
#pragma unroll
        for (int t = 0; t < 3; ++t) {
            const float sc = (t < 2) ? SRZ : SN;
            const int row = 32 * t + 16 * wl + n;
#pragma unroll
            for (int e = 0; e < 8; ++e) {
                A_h[t][e] = (short)bf_rne1(W_hh1[row * H_SZ + q * 8 + e] * sc);
                A_i[t][e] = (short)bf_rne1(W_ih1[row * H_SZ + q * 8 + e] * sc);
            }
#pragma unroll
            for (int r = 0; r < 4; ++r) {
                const int g = 32 * t + 16 * wl + 4 * q + r;
                C_h[t][r] = (t < 2) ? SRZ * (b_ih1[g] + b_hh1[g])
                                    : SN * b_hh1[g];
                if (t == 2) C_i3[r] = SN * b_ih1[g];
            }
        }
#pragma unroll
        for (int g = 0; g < 2; ++g)
#pragma unroll
            for (int r = 0; r < 4; ++r)
                hd[g][r] = h_in[B_SZ * H_SZ +
                                (base + g * 16 + n) * H_SZ + 16 * wl + 4 * q + r];
    }
    const f32x4 Z4 = {0.f, 0.f, 0.f, 0.f};
    const float bout = b_out[0];

    // ---- initial B fragments: pack h_in fp32 -> bf16 (both groups) ----
    short8 B0[2], B1[2];
#pragma unroll
    for (int g = 0; g < 2; ++g) {
        const int bg = base + g * 16 + n;
        union { short8 s8; unsigned u[4]; } f;
        float4 a = *(const float4*)&h_in[bg * H_SZ + q * 8];
        float4 b = *(const float4*)&h_in[bg * H_SZ + q * 8 + 4];
        f.u[0] = pk2(a.x, a.y); f.u[1] = pk2(a.z, a.w);
        f.u[2] = pk2(b.x, b.y); f.u[3] = pk2(b.z, b.w);
        B0[g] = f.s8;
        a = *(const float4*)&h_in[B_SZ * H_SZ + bg * H_SZ + q * 8];
        b = *(const float4*)&h_in[B_SZ * H_SZ + bg * H_SZ + q * 8 + 4];
        f.u[0] = pk2(a.x, a.y); f.u[1] = pk2(a.z, a.w);
        f.u[2] = pk2(b.x, b.y); f.u[3] = pk2(b.z, b.w);
        B1[g] = f.s8;
    }

    __syncthreads();   // x staged

#pragma unroll 1
    for (int i = 0; i <= S_LEN; ++i) {
        const int buf = i & 1;
        // ---------------- pre-barrier compute (both groups, interleaved) ---
        if (w < 2) {
            if (i < S_LEN) {
                // issue all 6 MFMAs up front (independent chains)
                const f32x4 g0r = MFMA(A_h[0], B0[0], C_h[0]);
                const f32x4 g0z = MFMA(A_h[1], B0[0], C_h[1]);
                const f32x4 g0n = MFMA(A_h[2], B0[0], C_h[2]);
                const f32x4 g1r = MFMA(A_h[0], B0[1], C_h[0]);
                const f32x4 g1z = MFMA(A_h[1], B0[1], C_h[1]);
                const f32x4 g1n = MFMA(A_h[2], B0[1], C_h[2]);
                const float xc0 = bits_f((unsigned)sxs[i * 32 + n] << 16);
                const float xc1 = bits_f((unsigned)sxs[i * 32 + 16 + n] << 16);
#pragma unroll
                for (int g = 0; g < 2; ++g) {
                    const float xc = g ? xc1 : xc0;
                    float hv4[4];
#pragma unroll
                    for (int r = 0; r < 4; ++r) {
                        const float gr = g ? g1r[r] : g0r[r];
                        const float gz = g ? g1z[r] : g0z[r];
                        const float gn = g ? g1n[r] : g0n[r];
                        const float rg = sigm_pre(fmaf(xc, wi0r[r], gr));
                        const float zg = sigm_pre(fmaf(xc, wi0z[r], gz));
                        const float ng = tanh_pre(fmaf(rg, gn,
                                                       fmaf(xc, wi0n[r], bi0n[r])));
                        const float hv = fmaf(zg, hd[g][r] - ng, ng);
                        hd[g][r] = hv;
                        hv4[r] = hv;
                    }
                    *(uint2*)&sh0s[buf][(g * 16 + n) * RS + 16 * wl + 4 * q] =
                        make_uint2(pk2(hv4[0], hv4[1]), pk2(hv4[2], hv4[3]));
                }
            }
        } else {
            if (i > 0) {
                const f32x4 u0r = MFMA(A_h[0], B1[0], C_h[0]);
                const f32x4 u0z = MFMA(A_h[1], B1[0], C_h[1]);
                const f32x4 u0n = MFMA(A_h[2], B1[0], C_h[2]);
                const f32x4 v0r = MFMA(A_i[0], B0[0], Z4);
                const f32x4 v0z = MFMA(A_i[1], B0[0], Z4);
                const f32x4 v0n = MFMA(A_i[2], B0[0], C_i3);
                const f32x4 u1r = MFMA(A_h[0], B1[1], C_h[0]);
                const f32x4 u1z = MFMA(A_h[1], B1[1], C_h[1]);
                const f32x4 u1n = MFMA(A_h[2], B1[1], C_h[2]);
                const f32x4 v1r = MFMA(A_i[0], B0[1], Z4);
                const f32x4 v1z = MFMA(A_i[1], B0[1], Z4);
                const f32x4 v1n = MFMA(A_i[2], B0[1], C_i3);
#pragma unroll
                for (int g = 0; g < 2; ++g) {
                    float hv4[4];
#pragma unroll
                    for (int r = 0; r < 4; ++r) {
                        const float ar = g ? u1r[r] + v1r[r] : u0r[r] + v0r[r];
                        const float az = g ? u1z[r] + v1z[r] : u0z[r] + v0z[r];
                        const float an = g ? u1n[r] : u0n[r];
                        const float bn_ = g ? v1n[r] : v0n[r];
                        const float rg = sigm_pre(ar);
                        const float zg = sigm_pre(az);
                        const float ng = tanh_pre(fmaf(rg, an, bn_));
                        const float hv = fmaf(zg, hd[g][r] - ng, ng);
                        hd[g][r] = hv;
                        hv4[r] = hv;
                    }
                    *(uint2*)&sh1s[buf][(g * 16 + n) * RS + 16 * wl + 4 * q] =
                        make_uint2(pk2(hv4[0], hv4[1]), pk2(hv4[2], hv4[3]));
                }
            }
        }

        __syncthreads();   // lgkm-only drain (no global ops in loop)

        // ---------------- post-barrier reads ----------------
        if (i < S_LEN) {
            B0[0] = *(const short8*)&sh0s[buf][n * RS + q * 8];
            B0[1] = *(const short8*)&sh0s[buf][(16 + n) * RS + q * 8];
            if (w >= 2 && i > 0) {
                B1[0] = *(const short8*)&sh1s[buf][n * RS + q * 8];
                B1[1] = *(const short8*)&sh1s[buf][(16 + n) * RS + q * 8];
            }
        }
        // y(i-1): wave wl handles group wl, dotting the bf16 h1 row.
        if (w < 2 && i > 0) {
            const uint4 d = *(const uint4*)&sh1s[buf][(wl * 16 + n) * RS + q * 8];
            float ys =       bits_f(d.x << 16) * wo8[0];
            ys = fmaf(bits_f(d.x & 0xffff0000u), wo8[1], ys);
            ys = fmaf(bits_f(d.y << 16),         wo8[2], ys);
            ys = fmaf(bits_f(d.y & 0xffff0000u), wo8[3], ys);
            ys = fmaf(bits_f(d.z << 16),         wo8[4], ys);
            ys = fmaf(bits_f(d.z & 0xffff0000u), wo8[5], ys);
            ys = fmaf(bits_f(d.w << 16),         wo8[6], ys);
            ys = fmaf(bits_f(d.w & 0xffff0000u), wo8[7], ys);
            ys += __shfl_xor(ys, 16);
            ys += __shfl_xor(ys, 32);
            if (lane < 16) sy[(i - 1) * 32 + wl * 16 + n] = ys;
        }
    }

    __syncthreads();   // sy complete

    // ---- flush y (coalesced float4 + bias) ----
    for (int s = tid; s < S_LEN * 8; s += 256) {
        const int t = s >> 3, c = s & 7;
        const float4 a = *(const float4*)&sy[t * 32 + c * 4];
        *(float4*)&out[t * B_SZ + base + c * 4] =
            make_float4(a.x + bout, a.y + bout, a.z + bout, a.w + bout);
    }

    // ---- final h_state: out = y (S*B) ++ h0 (B*H) ++ h1 (B*H) ----
    const int j = 16 * wl + 4 * q;
#pragma unroll
    for (int g = 0; g < 2; ++g) {
        const int bg = base + g * 16 + n;
        if (w < 2)
            *(float4*)&out[S_LEN * B_SZ + bg * H_SZ + j] =
                make_float4(hd[g][0], hd[g][1], hd[g][2], hd[g][3]);
        else
            *(float4*)&out[S_LEN * B_SZ + B_SZ * H_SZ + bg * H_SZ + j] =
                make_float4(hd[g][0], hd[g][1], hd[g][2], hd[g][3]);
    }
}

extern "C" void kernel_launch(void* const* d_in, const int* in_sizes, int n_in,
                              void* d_out, int out_size, void* d_ws, size_t ws_size,
                              hipStream_t stream) {
    (void)in_sizes; (void)n_in; (void)out_size; (void)d_ws; (void)ws_size;
    const float* x     = (const float*)d_in[0];
    const float* h_in  = (const float*)d_in[1];
    const float* W_ih0 = (const float*)d_in[2];
    const float* W_hh0 = (const float*)d_in[3];
    const float* b_ih0 = (const float*)d_in[4];
    const float* b_hh0 = (const float*)d_in[5];
    const float* W_ih1 = (const float*)d_in[6];
    const float* W_hh1 = (const float*)d_in[7];
    const float* b_ih1 = (const float*)d_in[8];
    const float* b_hh1 = (const float*)d_in[9];
    const float* W_out = (const float*)d_in[10];
    const float* b_out = (const float*)d_in[11];

    dim3 grid(B_SZ / 32);   // 256 blocks x 4 waves = 1024 waves (1/SIMD)
    dim3 block(256);
    gru_ilp2<<<grid, block, 0, stream>>>(x, h_in, W_ih0, W_hh0, b_ih0, b_hh0,
                                         W_ih1, W_hh1, b_ih1, b_hh1,
                                         W_out, b_out, (float*)d_out);
}